// Round 19
// baseline (203.282 us; speedup 1.0000x reference)
//
#include <hip/hip_runtime.h>
#include <hip/hip_bf16.h>
#include <stdint.h>

typedef unsigned short u16;
typedef __attribute__((ext_vector_type(4))) float f32x4;
typedef __attribute__((ext_vector_type(8))) short bf16x8;
typedef __attribute__((ext_vector_type(4))) unsigned int u32x4;

#define GLL16(src, dst) __builtin_amdgcn_global_load_lds( \
    (const __attribute__((address_space(1))) void*)(src), \
    (__attribute__((address_space(3))) void*)(dst), 16, 0, 0)

static __device__ __forceinline__ u16 f2bf(float x) {
    uint32_t u = __builtin_bit_cast(uint32_t, x);
    u += 0x7fffu + ((u >> 16) & 1u);
    return (u16)(u >> 16);
}

static __device__ __forceinline__ uint32_t cvtpk(float lo, float hi) {
    uint32_t r;
    asm("v_cvt_pk_bf16_f32 %0, %1, %2" : "=v"(r) : "v"(lo), "v"(hi));
    return r;
}

// ---------------- fused fp32 -> bf16 conversion: hs + all 4 weights ----------------
__global__ __launch_bounds__(256) void cvt_all(
        const float* __restrict__ hs, const float* __restrict__ w0,
        const float* __restrict__ w1, const float* __restrict__ w2,
        const float* __restrict__ w3, u16* __restrict__ dst) {
    int blk = blockIdx.x;
    const float* src;
    if (blk < 8192) {
        src = hs + (size_t)blk * 1024;
    } else {
        int j = blk - 8192;
        int wsel = j >> 10;
        const float* w = (wsel == 0) ? w0 : (wsel == 1) ? w1 : (wsel == 2) ? w2 : w3;
        src = w + (size_t)(j & 1023) * 1024;
    }
    int i = threadIdx.x;
    float4 v = ((const float4*)src)[i];
    ushort4 o;
    o.x = f2bf(v.x); o.y = f2bf(v.y); o.z = f2bf(v.z); o.w = f2bf(v.w);
    ((ushort4*)(dst + (size_t)blk * 1024))[i] = o;
}

// ---------------- fused QKV GEMM (R8-proven 2-barrier structure) ----------------
__global__ __launch_bounds__(256, 2) void gemm_qkv(
        const u16* __restrict__ A, const u16* __restrict__ W,
        const float* __restrict__ bq, const float* __restrict__ bk,
        const float* __restrict__ bv,
        u16* __restrict__ Qo, u16* __restrict__ Ko, u16* __restrict__ Vo) {
    __shared__ __align__(16) u16 As[2][128 * 32];
    __shared__ __align__(16) u16 Bs[2][128 * 32];
    const int tid = threadIdx.x;
    const int lane = tid & 63;
    const int w = tid >> 6, wm = w >> 1, wn = w & 1;
    const int l15 = lane & 15, l4 = lane >> 4;
    int v = (blockIdx.x & 7) * 192 + (blockIdx.x >> 3);
    int vy = v / 24, vx = v - vy * 24;
    const int m0 = vy * 128, n0 = vx * 128;
    const float SC2 = 0.03125f * 1.44269504088896f;

    f32x4 acc[4][4];
#pragma unroll
    for (int i = 0; i < 4; i++)
#pragma unroll
        for (int j = 0; j < 4; j++) acc[i][j] = f32x4{0.f, 0.f, 0.f, 0.f};

#define QKV_STAGE(buf, kt) do {                                            \
    _Pragma("unroll")                                                      \
    for (int i_ = 0; i_ < 2; i_++) {                                       \
        int c_ = tid + i_ * 256;                                           \
        int row_ = c_ >> 2, slot_ = c_ & 3;                                \
        int cc_ = slot_ ^ ((row_ >> 1) & 3);                               \
        GLL16(A + (size_t)(m0 + row_) * 1024 + (kt) + cc_ * 8, As[buf] + c_ * 8); \
    }                                                                      \
    _Pragma("unroll")                                                      \
    for (int i_ = 0; i_ < 2; i_++) {                                       \
        int c_ = tid + i_ * 256;                                           \
        int row_ = c_ >> 2, slot_ = c_ & 3;                                \
        int cc_ = slot_ ^ ((row_ >> 1) & 3);                               \
        GLL16(W + (size_t)(n0 + row_) * 1024 + (kt) + cc_ * 8, Bs[buf] + c_ * 8); \
    }                                                                      \
} while (0)

    QKV_STAGE(0, 0);
    __syncthreads();

    for (int kt = 0; kt < 1024; kt += 32) {
        const int cur = (kt >> 5) & 1;
        if (kt != 992) QKV_STAGE(cur ^ 1, kt + 32);

        bf16x8 af[4], bfr[4];
#pragma unroll
        for (int i = 0; i < 4; i++) {
            int row = wm * 64 + i * 16 + l15;
            int slot = l4 ^ ((row >> 1) & 3);
            af[i] = *(const bf16x8*)(As[cur] + row * 32 + slot * 8);
        }
#pragma unroll
        for (int j = 0; j < 4; j++) {
            int row = wn * 64 + j * 16 + l15;
            int slot = l4 ^ ((row >> 1) & 3);
            bfr[j] = *(const bf16x8*)(Bs[cur] + row * 32 + slot * 8);
        }
#pragma unroll
        for (int i = 0; i < 4; i++)
#pragma unroll
            for (int j = 0; j < 4; j++)
                acc[i][j] = __builtin_amdgcn_mfma_f32_16x16x32_bf16(af[i], bfr[j], acc[i][j], 0, 0, 0);
        __syncthreads();
    }
#undef QKV_STAGE

#pragma unroll
    for (int j = 0; j < 4; j++) {
        int col = n0 + wn * 64 + j * 16 + l15;
        int sel = col >> 10;
        float bvv = (sel == 0) ? bq[col] : (sel == 1) ? bk[col - 1024] : bv[col - 2048];
#pragma unroll
        for (int i = 0; i < 4; i++) {
            int rowb = m0 + wm * 64 + i * 16 + l4 * 4;
            if (sel == 0) {
#pragma unroll
                for (int r = 0; r < 4; r++)
                    Qo[(size_t)(rowb + r) * 1024 + col] = f2bf((acc[i][j][r] + bvv) * SC2);
            } else if (sel == 1) {
#pragma unroll
                for (int r = 0; r < 4; r++)
                    Ko[(size_t)(rowb + r) * 1024 + (col - 1024)] = f2bf(acc[i][j][r] + bvv);
            } else {
                int cc = col - 2048;
                int bb = rowb >> 11;
                int sp = ((m0 + wm * 64) & 2047) + (i >> 1) * 32 + l4 * 8 + (i & 1) * 4;
                int hh = cc >> 6, dd = cc & 63;
                ushort4 o;
                o.x = f2bf(acc[i][j][0] + bvv);
                o.y = f2bf(acc[i][j][1] + bvv);
                o.z = f2bf(acc[i][j][2] + bvv);
                o.w = f2bf(acc[i][j][3] + bvv);
                *(ushort4*)(Vo + ((size_t)((bb * 16 + hh) * 64 + dd)) * 2048 + sp) = o;
            }
        }
    }
}

// ---------------- output projection GEMM (R8-proven, fp32 out) ----------------
__global__ __launch_bounds__(256, 2) void gemm_o(
        const u16* __restrict__ A, const u16* __restrict__ W,
        const float* __restrict__ bias, float* __restrict__ out) {
    __shared__ __align__(16) u16 As[2][128 * 32];
    __shared__ __align__(16) u16 Bs[2][128 * 32];
    const int tid = threadIdx.x;
    const int lane = tid & 63;
    const int w = tid >> 6, wm = w >> 1, wn = w & 1;
    const int l15 = lane & 15, l4 = lane >> 4;
    int v = (blockIdx.x & 7) * 64 + (blockIdx.x >> 3);
    int vy = v >> 3, vx = v & 7;
    const int m0 = vy * 128, n0 = vx * 128;

    f32x4 acc[4][4];
#pragma unroll
    for (int i = 0; i < 4; i++)
#pragma unroll
        for (int j = 0; j < 4; j++) acc[i][j] = f32x4{0.f, 0.f, 0.f, 0.f};

#define O_STAGE(buf, kt) do {                                              \
    _Pragma("unroll")                                                      \
    for (int i_ = 0; i_ < 2; i_++) {                                       \
        int c_ = tid + i_ * 256;                                           \
        int row_ = c_ >> 2, slot_ = c_ & 3;                                \
        int cc_ = slot_ ^ ((row_ >> 1) & 3);                               \
        GLL16(A + (size_t)(m0 + row_) * 1024 + (kt) + cc_ * 8, As[buf] + c_ * 8); \
    }                                                                      \
    _Pragma("unroll")                                                      \
    for (int i_ = 0; i_ < 2; i_++) {                                       \
        int c_ = tid + i_ * 256;                                           \
        int row_ = c_ >> 2, slot_ = c_ & 3;                                \
        int cc_ = slot_ ^ ((row_ >> 1) & 3);                               \
        GLL16(W + (size_t)(n0 + row_) * 1024 + (kt) + cc_ * 8, Bs[buf] + c_ * 8); \
    }                                                                      \
} while (0)

    O_STAGE(0, 0);
    __syncthreads();

    for (int kt = 0; kt < 1024; kt += 32) {
        const int cur = (kt >> 5) & 1;
        if (kt != 992) O_STAGE(cur ^ 1, kt + 32);

        bf16x8 af[4], bfr[4];
#pragma unroll
        for (int i = 0; i < 4; i++) {
            int row = wm * 64 + i * 16 + l15;
            int slot = l4 ^ ((row >> 1) & 3);
            af[i] = *(const bf16x8*)(As[cur] + row * 32 + slot * 8);
        }
#pragma unroll
        for (int j = 0; j < 4; j++) {
            int row = wn * 64 + j * 16 + l15;
            int slot = l4 ^ ((row >> 1) & 3);
            bfr[j] = *(const bf16x8*)(Bs[cur] + row * 32 + slot * 8);
        }
#pragma unroll
        for (int i = 0; i < 4; i++)
#pragma unroll
            for (int j = 0; j < 4; j++)
                acc[i][j] = __builtin_amdgcn_mfma_f32_16x16x32_bf16(af[i], bfr[j], acc[i][j], 0, 0, 0);
        __syncthreads();
    }
#undef O_STAGE

#pragma unroll
    for (int j = 0; j < 4; j++) {
        int col = n0 + wn * 64 + j * 16 + l15;
        float bvv = bias[col];
#pragma unroll
        for (int i = 0; i < 4; i++) {
            int rowb = m0 + wm * 64 + i * 16 + l4 * 4;
#pragma unroll
            for (int r = 0; r < 4; r++)
                out[(size_t)(rowb + r) * 1024 + col] = acc[i][j][r] + bvv;
        }
    }
}

// ---------------- fused flash attention (R8 body, 4-buffer / 2-tiles-per-barrier) ----------------
// 1D grid 1024, XCD swizzle (K/V L2-resident). 4 waves x 32 q-rows, KVBLK=64.
// R13's barrier-halving goal WITHOUT its failure modes: tiles stay 64x64
// (identical swizzle to R8 -> zero new bank conflicts) and the register body
// is R8's run twice (no VGPR growth). Period: stage tiles t+2,t+3 into bufs
// (t+2)%4,(t+3)%4; compute tiles t,t+1 from bufs t%4,(t+1)%4; ONE barrier.
// 16 barriers (was 32); prefetch depth 2 (drain at barrier covers loads issued
// a full double-period earlier). LDS 64 KB -> 2 blocks/CU (= measured R8
// residency, nothing lost).
__global__ __launch_bounds__(256, 3) void attn_fused(
        const u16* __restrict__ Q, const u16* __restrict__ K,
        const u16* __restrict__ Vt, const float* __restrict__ mask,
        u16* __restrict__ ctx) {
    __shared__ __align__(16) u16 Ks[4][64 * 64];    // [kv][d], swizzled slots
    __shared__ __align__(16) u16 Vs[4][64 * 64];    // [d][s'], swizzled slots

    const int tid = threadIdx.x, lane = tid & 63, w = tid >> 6;
    const int l15 = lane & 15, l4 = lane >> 4;
    const int bid = blockIdx.x;
    const int inner = bid >> 3;
    const int bh = ((inner >> 4) << 3) | (bid & 7);
    const int b = bh >> 4, h = bh & 15;
    const int qw = (inner & 15) * 128 + w * 32;
    const float THR2 = 8.0f;

    const u16* Qg = Q + (size_t)b * 2048 * 1024 + h * 64;
    const u16* Kg = K + (size_t)b * 2048 * 1024 + h * 64;
    const u16* Vg = Vt + (size_t)bh * 64 * 2048;
    const float* mp = mask + b * 2048;

    // ---- wave-redundant mask scan: 64 lanes x 8 float4 = 2048 ----
    bool anym;
    {
        bool bad = false;
#pragma unroll
        for (int i = 0; i < 8; i++) {
            float4 a = ((const float4*)mp)[lane * 8 + i];
            bad |= (a.x == 0.f) | (a.y == 0.f) | (a.z == 0.f) | (a.w == 0.f);
        }
        anym = (__ballot(bad) != 0ull);
    }

#define STAGE_KV(buf, kvbase) do {                                         \
    _Pragma("unroll")                                                      \
    for (int i_ = 0; i_ < 2; i_++) {                                       \
        int c_ = tid + i_ * 256;                                           \
        int row_ = c_ >> 3, slot_ = c_ & 7;                                \
        int cc_ = slot_ ^ (row_ & 7);                                      \
        GLL16(Kg + (size_t)((kvbase) + row_) * 1024 + cc_ * 8, Ks[buf] + c_ * 8); \
    }                                                                      \
    _Pragma("unroll")                                                      \
    for (int i_ = 0; i_ < 2; i_++) {                                       \
        int c_ = tid + i_ * 256;                                           \
        int row_ = c_ >> 3, slot_ = c_ & 7;                                \
        int cc_ = slot_ ^ (row_ & 7);                                      \
        GLL16(Vg + (size_t)row_ * 2048 + (kvbase) + cc_ * 8, Vs[buf] + c_ * 8); \
    }                                                                      \
} while (0)

    // hoist Q fragments (B-operand layout), already scaled by log2e/32
    bf16x8 qfr[2][2];
#pragma unroll
    for (int qi = 0; qi < 2; qi++)
#pragma unroll
        for (int kf = 0; kf < 2; kf++)
            qfr[qi][kf] = *(const bf16x8*)(Qg + (size_t)(qw + qi * 16 + l15) * 1024 + kf * 32 + l4 * 8);

    // q-mask 0/1 flag (cold path only)
    float mq01[2];
#pragma unroll
    for (int qi = 0; qi < 2; qi++)
        mq01[qi] = (mp[qw + qi * 16 + l15] != 0.f) ? 1.f : 0.f;

    float m_run[2] = {0.f, 0.f};
    f32x4 acc_l[2];      // denominator via ones-MFMA
    f32x4 oaccT[4][2];   // O^T: [d-frag][q-frag]
#pragma unroll
    for (int qi = 0; qi < 2; qi++) acc_l[qi] = f32x4{0.f, 0.f, 0.f, 0.f};
#pragma unroll
    for (int df = 0; df < 4; df++)
#pragma unroll
        for (int qi = 0; qi < 2; qi++) oaccT[df][qi] = f32x4{0.f, 0.f, 0.f, 0.f};

    const u32x4 ones4 = u32x4{0x3F803F80u, 0x3F803F80u, 0x3F803F80u, 0x3F803F80u};
    const bf16x8 ones = __builtin_bit_cast(bf16x8, ones4);

    STAGE_KV(0, 0);
    STAGE_KV(1, 64);
    __syncthreads();

    for (int it = 0; it < 32; it += 2) {
        // stage the NEXT pair (depth-2 prefetch, bufs distinct mod 4)
        if (it + 2 < 32) STAGE_KV((it + 2) & 3, (it + 2) * 64);
        if (it + 3 < 32) STAGE_KV((it + 3) & 3, (it + 3) * 64);

#pragma unroll
        for (int sub = 0; sub < 2; sub++) {
            const int cur = (it + sub) & 3;
            const int kv0 = (it + sub) * 64;

            // ---- S^T = K Q^T (emits base-2 scores; Q pre-scaled) ----
            bf16x8 kfr[4][2];
#pragma unroll
            for (int kvf = 0; kvf < 4; kvf++)
#pragma unroll
                for (int kf = 0; kf < 2; kf++) {
                    int row = kvf * 16 + l15;
                    int slot = (kf * 4 + l4) ^ (row & 7);
                    kfr[kvf][kf] = *(const bf16x8*)(Ks[cur] + row * 64 + slot * 8);
                }
            f32x4 p[4][2];
#pragma unroll
            for (int kvf = 0; kvf < 4; kvf++)
#pragma unroll
                for (int qi = 0; qi < 2; qi++) p[kvf][qi] = f32x4{0.f, 0.f, 0.f, 0.f};
            __builtin_amdgcn_s_setprio(1);
#pragma unroll
            for (int kvf = 0; kvf < 4; kvf++)
#pragma unroll
                for (int qi = 0; qi < 2; qi++)
#pragma unroll
                    for (int kf = 0; kf < 2; kf++)
                        p[kvf][qi] = __builtin_amdgcn_mfma_f32_16x16x32_bf16(kfr[kvf][kf], qfr[qi][kf], p[kvf][qi], 0, 0, 0);
            __builtin_amdgcn_s_setprio(0);

            // ---- cold masked path: p = p*mq01 + kbias ----
            if (anym) {
                float4 mkv[4];
#pragma unroll
                for (int kvf = 0; kvf < 4; kvf++)
                    mkv[kvf] = ((const float4*)(mp + kv0))[kvf * 4 + l4];
#pragma unroll
                for (int qi = 0; qi < 2; qi++)
#pragma unroll
                    for (int kvf = 0; kvf < 4; kvf++)
#pragma unroll
                        for (int r = 0; r < 4; r++) {
                            float bb = (mkv[kvf][r] != 0.f) ? 0.f : -1e12f;
                            p[kvf][qi][r] = __builtin_fmaf(p[kvf][qi][r], mq01[qi], bb);
                        }
            }

            // ---- lane-local maxima; guard vs m_run + THR ----
            float t[2];
#pragma unroll
            for (int qi = 0; qi < 2; qi++) {
                float a0 = fmaxf(fmaxf(p[0][qi][0], p[0][qi][1]), fmaxf(p[0][qi][2], p[0][qi][3]));
                float a1 = fmaxf(fmaxf(p[1][qi][0], p[1][qi][1]), fmaxf(p[1][qi][2], p[1][qi][3]));
                float a2 = fmaxf(fmaxf(p[2][qi][0], p[2][qi][1]), fmaxf(p[2][qi][2], p[2][qi][3]));
                float a3 = fmaxf(fmaxf(p[3][qi][0], p[3][qi][1]), fmaxf(p[3][qi][2], p[3][qi][3]));
                t[qi] = fmaxf(fmaxf(a0, a1), fmaxf(a2, a3));
            }
            if (!__all((t[0] <= m_run[0] + THR2) && (t[1] <= m_run[1] + THR2))) {
                // cold rescale: cross-lane max, update m_run, scale accumulators
#pragma unroll
                for (int qi = 0; qi < 2; qi++) {
                    float tt = fmaxf(t[qi], __shfl_xor(t[qi], 16));
                    tt = fmaxf(tt, __shfl_xor(tt, 32));
                    float mn = fmaxf(m_run[qi], tt);
                    float sc = __builtin_amdgcn_exp2f(m_run[qi] - mn);
                    m_run[qi] = mn;
                    acc_l[qi] *= sc;
#pragma unroll
                    for (int df = 0; df < 4; df++) oaccT[df][qi] *= sc;
                }
            }
            // ---- exp2; m_run==0 fast path has no subtract ----
            if (__all((m_run[0] == 0.f) & (m_run[1] == 0.f))) {
#pragma unroll
                for (int qi = 0; qi < 2; qi++)
#pragma unroll
                    for (int kvf = 0; kvf < 4; kvf++)
#pragma unroll
                        for (int r = 0; r < 4; r++)
                            p[kvf][qi][r] = __builtin_amdgcn_exp2f(p[kvf][qi][r]);
            } else {
#pragma unroll
                for (int qi = 0; qi < 2; qi++)
#pragma unroll
                    for (int kvf = 0; kvf < 4; kvf++)
#pragma unroll
                        for (int r = 0; r < 4; r++)
                            p[kvf][qi][r] = __builtin_amdgcn_exp2f(p[kvf][qi][r] - m_run[qi]);
            }

            // ---- pb = lane-local P quads packed to bf16 ----
            bf16x8 pb[2][2];
#pragma unroll
            for (int qi = 0; qi < 2; qi++)
#pragma unroll
                for (int kf = 0; kf < 2; kf++) {
                    u32x4 tq;
                    tq.x = cvtpk(p[2 * kf][qi][0], p[2 * kf][qi][1]);
                    tq.y = cvtpk(p[2 * kf][qi][2], p[2 * kf][qi][3]);
                    tq.z = cvtpk(p[2 * kf + 1][qi][0], p[2 * kf + 1][qi][1]);
                    tq.w = cvtpk(p[2 * kf + 1][qi][2], p[2 * kf + 1][qi][3]);
                    pb[qi][kf] = __builtin_bit_cast(bf16x8, tq);
                }

            // V fragments after softmax (kept out of the VALU-phase live set)
            bf16x8 vfr[4][2];
#pragma unroll
            for (int df = 0; df < 4; df++)
#pragma unroll
                for (int kf = 0; kf < 2; kf++) {
                    int row = df * 16 + l15;
                    int slot = (kf * 4 + l4) ^ (row & 7);
                    vfr[df][kf] = *(const bf16x8*)(Vs[cur] + row * 64 + slot * 8);
                }

            // ---- O^T += V^T P^T ; l += ones^T P^T ----
            __builtin_amdgcn_s_setprio(1);
#pragma unroll
            for (int df = 0; df < 4; df++)
#pragma unroll
                for (int qi = 0; qi < 2; qi++)
#pragma unroll
                    for (int kf = 0; kf < 2; kf++)
                        oaccT[df][qi] = __builtin_amdgcn_mfma_f32_16x16x32_bf16(vfr[df][kf], pb[qi][kf], oaccT[df][qi], 0, 0, 0);
#pragma unroll
            for (int qi = 0; qi < 2; qi++)
#pragma unroll
                for (int kf = 0; kf < 2; kf++)
                    acc_l[qi] = __builtin_amdgcn_mfma_f32_16x16x32_bf16(ones, pb[qi][kf], acc_l[qi], 0, 0, 0);
            __builtin_amdgcn_s_setprio(0);
        }

        __syncthreads();   // one barrier per 2 tiles: drains this period's
                           // prefetch + releases bufs it%4,(it+1)%4 for reuse
    }

    // ---- epilogue: ctx[token][h*64+d] = O^T / l ----
#pragma unroll
    for (int qi = 0; qi < 2; qi++) {
        float rl = 1.0f / acc_l[qi][0];
        int tok = qw + qi * 16 + l15;
#pragma unroll
        for (int df = 0; df < 4; df++) {
            uint2 o;
            o.x = cvtpk(oaccT[df][qi][0] * rl, oaccT[df][qi][1] * rl);
            o.y = cvtpk(oaccT[df][qi][2] * rl, oaccT[df][qi][3] * rl);
            *(uint2*)(ctx + (size_t)(b * 2048 + tok) * 1024 + h * 64 + df * 16 + l4 * 4) = o;
        }
    }
#undef STAGE_KV
}

extern "C" void kernel_launch(void* const* d_in, const int* in_sizes, int n_in,
                              void* d_out, int out_size, void* d_ws, size_t ws_size,
                              hipStream_t stream) {
    const float* hs    = (const float*)d_in[0];
    const float* masks = (const float*)d_in[1];
    const float* Wq = (const float*)d_in[2];
    const float* bq = (const float*)d_in[3];
    const float* Wk = (const float*)d_in[4];
    const float* bk = (const float*)d_in[5];
    const float* Wv = (const float*)d_in[6];
    const float* bv = (const float*)d_in[7];
    const float* Wo = (const float*)d_in[8];
    const float* bo = (const float*)d_in[9];

    const int NT = 4 * 2048;   // 8192 tokens
    const int H = 1024;

    u16* hs_b = (u16*)d_ws;                       // [8192,1024]
    u16* w_b  = hs_b + (size_t)NT * H;            // [Wq|Wk|Wv|Wo] 4x[1024,1024]
    u16* wo_b = w_b + (size_t)3 * H * H;
    u16* Qb   = w_b + (size_t)4 * H * H;          // [8192,1024] (pre-scaled)
    u16* Kb   = Qb + (size_t)NT * H;              // [8192,1024]
    u16* Vtb  = Kb + (size_t)NT * H;              // [64][64][2048] s'-permuted
    u16* Cb   = hs_b;                             // attn output reuses hidden buffer

    // one fused conversion dispatch: hs + 4 weights into contiguous ws region
    cvt_all<<<12288, 256, 0, stream>>>(hs, Wq, Wk, Wv, Wo, hs_b);

    gemm_qkv<<<1536, 256, 0, stream>>>(hs_b, w_b, bq, bk, bv, Qb, Kb, Vtb);

    attn_fused<<<1024, 256, 0, stream>>>(Qb, Kb, Vtb, masks, Cb);

    gemm_o<<<512, 256, 0, stream>>>(Cb, wo_b, bo, (float*)d_out);
}

// Round 20
// 195.727 us; speedup vs baseline: 1.0386x; 1.0386x over previous
//
#include <hip/hip_runtime.h>
#include <hip/hip_bf16.h>
#include <stdint.h>

typedef unsigned short u16;
typedef __attribute__((ext_vector_type(4))) float f32x4;
typedef __attribute__((ext_vector_type(8))) short bf16x8;
typedef __attribute__((ext_vector_type(4))) unsigned int u32x4;

#define GLL16(src, dst) __builtin_amdgcn_global_load_lds( \
    (const __attribute__((address_space(1))) void*)(src), \
    (__attribute__((address_space(3))) void*)(dst), 16, 0, 0)

static __device__ __forceinline__ u16 f2bf(float x) {
    uint32_t u = __builtin_bit_cast(uint32_t, x);
    u += 0x7fffu + ((u >> 16) & 1u);
    return (u16)(u >> 16);
}

static __device__ __forceinline__ uint32_t cvtpk(float lo, float hi) {
    uint32_t r;
    asm("v_cvt_pk_bf16_f32 %0, %1, %2" : "=v"(r) : "v"(lo), "v"(hi));
    return r;
}

// ---------------- fused fp32 -> bf16 conversion: hs + all 4 weights ----------------
// dst contiguous in ws: [hs_b (8192x1024) | Wq | Wk | Wv | Wo]. One dispatch
// (R14-verified: saves ~3 us vs two dispatches).
__global__ __launch_bounds__(256) void cvt_all(
        const float* __restrict__ hs, const float* __restrict__ w0,
        const float* __restrict__ w1, const float* __restrict__ w2,
        const float* __restrict__ w3, u16* __restrict__ dst) {
    int blk = blockIdx.x;
    const float* src;
    if (blk < 8192) {
        src = hs + (size_t)blk * 1024;
    } else {
        int j = blk - 8192;
        int wsel = j >> 10;
        const float* w = (wsel == 0) ? w0 : (wsel == 1) ? w1 : (wsel == 2) ? w2 : w3;
        src = w + (size_t)(j & 1023) * 1024;
    }
    int i = threadIdx.x;
    float4 v = ((const float4*)src)[i];
    ushort4 o;
    o.x = f2bf(v.x); o.y = f2bf(v.y); o.z = f2bf(v.z); o.w = f2bf(v.w);
    ((ushort4*)(dst + (size_t)blk * 1024))[i] = o;
}

// ---------------- fused QKV GEMM (R8-proven 2-barrier structure) ----------------
// R9/R12/R17 all measured worse (counted-vmcnt, phased big-tile, depth-2
// triple-buffer): this 128^2/BK32/double-buffer shape is the structure optimum.
__global__ __launch_bounds__(256, 2) void gemm_qkv(
        const u16* __restrict__ A, const u16* __restrict__ W,
        const float* __restrict__ bq, const float* __restrict__ bk,
        const float* __restrict__ bv,
        u16* __restrict__ Qo, u16* __restrict__ Ko, u16* __restrict__ Vo) {
    __shared__ __align__(16) u16 As[2][128 * 32];
    __shared__ __align__(16) u16 Bs[2][128 * 32];
    const int tid = threadIdx.x;
    const int lane = tid & 63;
    const int w = tid >> 6, wm = w >> 1, wn = w & 1;
    const int l15 = lane & 15, l4 = lane >> 4;
    int v = (blockIdx.x & 7) * 192 + (blockIdx.x >> 3);
    int vy = v / 24, vx = v - vy * 24;
    const int m0 = vy * 128, n0 = vx * 128;
    const float SC2 = 0.03125f * 1.44269504088896f;

    f32x4 acc[4][4];
#pragma unroll
    for (int i = 0; i < 4; i++)
#pragma unroll
        for (int j = 0; j < 4; j++) acc[i][j] = f32x4{0.f, 0.f, 0.f, 0.f};

#define QKV_STAGE(buf, kt) do {                                            \
    _Pragma("unroll")                                                      \
    for (int i_ = 0; i_ < 2; i_++) {                                       \
        int c_ = tid + i_ * 256;                                           \
        int row_ = c_ >> 2, slot_ = c_ & 3;                                \
        int cc_ = slot_ ^ ((row_ >> 1) & 3);                               \
        GLL16(A + (size_t)(m0 + row_) * 1024 + (kt) + cc_ * 8, As[buf] + c_ * 8); \
    }                                                                      \
    _Pragma("unroll")                                                      \
    for (int i_ = 0; i_ < 2; i_++) {                                       \
        int c_ = tid + i_ * 256;                                           \
        int row_ = c_ >> 2, slot_ = c_ & 3;                                \
        int cc_ = slot_ ^ ((row_ >> 1) & 3);                               \
        GLL16(W + (size_t)(n0 + row_) * 1024 + (kt) + cc_ * 8, Bs[buf] + c_ * 8); \
    }                                                                      \
} while (0)

    QKV_STAGE(0, 0);
    __syncthreads();

    for (int kt = 0; kt < 1024; kt += 32) {
        const int cur = (kt >> 5) & 1;
        if (kt != 992) QKV_STAGE(cur ^ 1, kt + 32);

        bf16x8 af[4], bfr[4];
#pragma unroll
        for (int i = 0; i < 4; i++) {
            int row = wm * 64 + i * 16 + l15;
            int slot = l4 ^ ((row >> 1) & 3);
            af[i] = *(const bf16x8*)(As[cur] + row * 32 + slot * 8);
        }
#pragma unroll
        for (int j = 0; j < 4; j++) {
            int row = wn * 64 + j * 16 + l15;
            int slot = l4 ^ ((row >> 1) & 3);
            bfr[j] = *(const bf16x8*)(Bs[cur] + row * 32 + slot * 8);
        }
#pragma unroll
        for (int i = 0; i < 4; i++)
#pragma unroll
            for (int j = 0; j < 4; j++)
                acc[i][j] = __builtin_amdgcn_mfma_f32_16x16x32_bf16(af[i], bfr[j], acc[i][j], 0, 0, 0);
        __syncthreads();
    }
#undef QKV_STAGE

#pragma unroll
    for (int j = 0; j < 4; j++) {
        int col = n0 + wn * 64 + j * 16 + l15;
        int sel = col >> 10;
        float bvv = (sel == 0) ? bq[col] : (sel == 1) ? bk[col - 1024] : bv[col - 2048];
#pragma unroll
        for (int i = 0; i < 4; i++) {
            int rowb = m0 + wm * 64 + i * 16 + l4 * 4;
            if (sel == 0) {
#pragma unroll
                for (int r = 0; r < 4; r++)
                    Qo[(size_t)(rowb + r) * 1024 + col] = f2bf((acc[i][j][r] + bvv) * SC2);
            } else if (sel == 1) {
#pragma unroll
                for (int r = 0; r < 4; r++)
                    Ko[(size_t)(rowb + r) * 1024 + (col - 1024)] = f2bf(acc[i][j][r] + bvv);
            } else {
                int cc = col - 2048;
                int bb = rowb >> 11;
                int sp = ((m0 + wm * 64) & 2047) + (i >> 1) * 32 + l4 * 8 + (i & 1) * 4;
                int hh = cc >> 6, dd = cc & 63;
                ushort4 o;
                o.x = f2bf(acc[i][j][0] + bvv);
                o.y = f2bf(acc[i][j][1] + bvv);
                o.z = f2bf(acc[i][j][2] + bvv);
                o.w = f2bf(acc[i][j][3] + bvv);
                *(ushort4*)(Vo + ((size_t)((bb * 16 + hh) * 64 + dd)) * 2048 + sp) = o;
            }
        }
    }
}

// ---------------- output projection GEMM (R8-proven, fp32 out) ----------------
__global__ __launch_bounds__(256, 2) void gemm_o(
        const u16* __restrict__ A, const u16* __restrict__ W,
        const float* __restrict__ bias, float* __restrict__ out) {
    __shared__ __align__(16) u16 As[2][128 * 32];
    __shared__ __align__(16) u16 Bs[2][128 * 32];
    const int tid = threadIdx.x;
    const int lane = tid & 63;
    const int w = tid >> 6, wm = w >> 1, wn = w & 1;
    const int l15 = lane & 15, l4 = lane >> 4;
    int v = (blockIdx.x & 7) * 64 + (blockIdx.x >> 3);
    int vy = v >> 3, vx = v & 7;
    const int m0 = vy * 128, n0 = vx * 128;

    f32x4 acc[4][4];
#pragma unroll
    for (int i = 0; i < 4; i++)
#pragma unroll
        for (int j = 0; j < 4; j++) acc[i][j] = f32x4{0.f, 0.f, 0.f, 0.f};

#define O_STAGE(buf, kt) do {                                              \
    _Pragma("unroll")                                                      \
    for (int i_ = 0; i_ < 2; i_++) {                                       \
        int c_ = tid + i_ * 256;                                           \
        int row_ = c_ >> 2, slot_ = c_ & 3;                                \
        int cc_ = slot_ ^ ((row_ >> 1) & 3);                               \
        GLL16(A + (size_t)(m0 + row_) * 1024 + (kt) + cc_ * 8, As[buf] + c_ * 8); \
    }                                                                      \
    _Pragma("unroll")                                                      \
    for (int i_ = 0; i_ < 2; i_++) {                                       \
        int c_ = tid + i_ * 256;                                           \
        int row_ = c_ >> 2, slot_ = c_ & 3;                                \
        int cc_ = slot_ ^ ((row_ >> 1) & 3);                               \
        GLL16(W + (size_t)(n0 + row_) * 1024 + (kt) + cc_ * 8, Bs[buf] + c_ * 8); \
    }                                                                      \
} while (0)

    O_STAGE(0, 0);
    __syncthreads();

    for (int kt = 0; kt < 1024; kt += 32) {
        const int cur = (kt >> 5) & 1;
        if (kt != 992) O_STAGE(cur ^ 1, kt + 32);

        bf16x8 af[4], bfr[4];
#pragma unroll
        for (int i = 0; i < 4; i++) {
            int row = wm * 64 + i * 16 + l15;
            int slot = l4 ^ ((row >> 1) & 3);
            af[i] = *(const bf16x8*)(As[cur] + row * 32 + slot * 8);
        }
#pragma unroll
        for (int j = 0; j < 4; j++) {
            int row = wn * 64 + j * 16 + l15;
            int slot = l4 ^ ((row >> 1) & 3);
            bfr[j] = *(const bf16x8*)(Bs[cur] + row * 32 + slot * 8);
        }
#pragma unroll
        for (int i = 0; i < 4; i++)
#pragma unroll
            for (int j = 0; j < 4; j++)
                acc[i][j] = __builtin_amdgcn_mfma_f32_16x16x32_bf16(af[i], bfr[j], acc[i][j], 0, 0, 0);
        __syncthreads();
    }
#undef O_STAGE

#pragma unroll
    for (int j = 0; j < 4; j++) {
        int col = n0 + wn * 64 + j * 16 + l15;
        float bvv = bias[col];
#pragma unroll
        for (int i = 0; i < 4; i++) {
            int rowb = m0 + wm * 64 + i * 16 + l4 * 4;
#pragma unroll
            for (int r = 0; r < 4; r++)
                out[(size_t)(rowb + r) * 1024 + col] = acc[i][j][r] + bvv;
        }
    }
}

// ---------------- fused flash attention (R8/R16-proven kernel, (256,3)) ----------------
// 1D grid 1024, XCD swizzle (K/V L2-resident). 4 waves x 32 q-rows, KVBLK=64.
// {STAGE(next) -> compute -> __syncthreads}; vfr after softmax. Design space
// closed by measurement (R9-R15, R19): (256,3) optimal; KVBLK=64; 128 q/block;
// LDS dbuf 2-deep; vfr post-softmax; 1 barrier/tile (2-tiles/barrier grew VGPR
// 80->112 and lost occupancy, R19). Softmax: prescaled-Q base-2, zero
// cross-lane hot path, ones-MFMA denominator, defer-max.
__global__ __launch_bounds__(256, 3) void attn_fused(
        const u16* __restrict__ Q, const u16* __restrict__ K,
        const u16* __restrict__ Vt, const float* __restrict__ mask,
        u16* __restrict__ ctx) {
    __shared__ __align__(16) u16 Ks[2][64 * 64];    // [kv][d], swizzled slots
    __shared__ __align__(16) u16 Vs[2][64 * 64];    // [d][s'], swizzled slots

    const int tid = threadIdx.x, lane = tid & 63, w = tid >> 6;
    const int l15 = lane & 15, l4 = lane >> 4;
    const int bid = blockIdx.x;
    const int inner = bid >> 3;
    const int bh = ((inner >> 4) << 3) | (bid & 7);
    const int b = bh >> 4, h = bh & 15;
    const int qw = (inner & 15) * 128 + w * 32;
    const float THR2 = 8.0f;

    const u16* Qg = Q + (size_t)b * 2048 * 1024 + h * 64;
    const u16* Kg = K + (size_t)b * 2048 * 1024 + h * 64;
    const u16* Vg = Vt + (size_t)bh * 64 * 2048;
    const float* mp = mask + b * 2048;

    // ---- wave-redundant mask scan: 64 lanes x 8 float4 = 2048 ----
    bool anym;
    {
        bool bad = false;
#pragma unroll
        for (int i = 0; i < 8; i++) {
            float4 a = ((const float4*)mp)[lane * 8 + i];
            bad |= (a.x == 0.f) | (a.y == 0.f) | (a.z == 0.f) | (a.w == 0.f);
        }
        anym = (__ballot(bad) != 0ull);
    }

#define STAGE_KV(buf, kvbase) do {                                         \
    _Pragma("unroll")                                                      \
    for (int i_ = 0; i_ < 2; i_++) {                                       \
        int c_ = tid + i_ * 256;                                           \
        int row_ = c_ >> 3, slot_ = c_ & 7;                                \
        int cc_ = slot_ ^ (row_ & 7);                                      \
        GLL16(Kg + (size_t)((kvbase) + row_) * 1024 + cc_ * 8, Ks[buf] + c_ * 8); \
    }                                                                      \
    _Pragma("unroll")                                                      \
    for (int i_ = 0; i_ < 2; i_++) {                                       \
        int c_ = tid + i_ * 256;                                           \
        int row_ = c_ >> 3, slot_ = c_ & 7;                                \
        int cc_ = slot_ ^ (row_ & 7);                                      \
        GLL16(Vg + (size_t)row_ * 2048 + (kvbase) + cc_ * 8, Vs[buf] + c_ * 8); \
    }                                                                      \
} while (0)

    // hoist Q fragments (B-operand layout), already scaled by log2e/32
    bf16x8 qfr[2][2];
#pragma unroll
    for (int qi = 0; qi < 2; qi++)
#pragma unroll
        for (int kf = 0; kf < 2; kf++)
            qfr[qi][kf] = *(const bf16x8*)(Qg + (size_t)(qw + qi * 16 + l15) * 1024 + kf * 32 + l4 * 8);

    // q-mask 0/1 flag (cold path only)
    float mq01[2];
#pragma unroll
    for (int qi = 0; qi < 2; qi++)
        mq01[qi] = (mp[qw + qi * 16 + l15] != 0.f) ? 1.f : 0.f;

    float m_run[2] = {0.f, 0.f};
    f32x4 acc_l[2];      // denominator via ones-MFMA
    f32x4 oaccT[4][2];   // O^T: [d-frag][q-frag]
#pragma unroll
    for (int qi = 0; qi < 2; qi++) acc_l[qi] = f32x4{0.f, 0.f, 0.f, 0.f};
#pragma unroll
    for (int df = 0; df < 4; df++)
#pragma unroll
        for (int qi = 0; qi < 2; qi++) oaccT[df][qi] = f32x4{0.f, 0.f, 0.f, 0.f};

    const u32x4 ones4 = u32x4{0x3F803F80u, 0x3F803F80u, 0x3F803F80u, 0x3F803F80u};
    const bf16x8 ones = __builtin_bit_cast(bf16x8, ones4);

    STAGE_KV(0, 0);
    __syncthreads();

    for (int it = 0; it < 32; ++it) {
        const int cur = it & 1;
        const int kv0 = it * 64;

        if (it != 31) STAGE_KV(cur ^ 1, kv0 + 64);

        // ---- S^T = K Q^T (emits base-2 scores; Q pre-scaled) ----
        bf16x8 kfr[4][2];
#pragma unroll
        for (int kvf = 0; kvf < 4; kvf++)
#pragma unroll
            for (int kf = 0; kf < 2; kf++) {
                int row = kvf * 16 + l15;
                int slot = (kf * 4 + l4) ^ (row & 7);
                kfr[kvf][kf] = *(const bf16x8*)(Ks[cur] + row * 64 + slot * 8);
            }
        f32x4 p[4][2];
#pragma unroll
        for (int kvf = 0; kvf < 4; kvf++)
#pragma unroll
            for (int qi = 0; qi < 2; qi++) p[kvf][qi] = f32x4{0.f, 0.f, 0.f, 0.f};
        __builtin_amdgcn_s_setprio(1);
#pragma unroll
        for (int kvf = 0; kvf < 4; kvf++)
#pragma unroll
            for (int qi = 0; qi < 2; qi++)
#pragma unroll
                for (int kf = 0; kf < 2; kf++)
                    p[kvf][qi] = __builtin_amdgcn_mfma_f32_16x16x32_bf16(kfr[kvf][kf], qfr[qi][kf], p[kvf][qi], 0, 0, 0);
        __builtin_amdgcn_s_setprio(0);

        // ---- cold masked path: p = p*mq01 + kbias ----
        if (anym) {
            float4 mkv[4];
#pragma unroll
            for (int kvf = 0; kvf < 4; kvf++)
                mkv[kvf] = ((const float4*)(mp + kv0))[kvf * 4 + l4];
#pragma unroll
            for (int qi = 0; qi < 2; qi++)
#pragma unroll
                for (int kvf = 0; kvf < 4; kvf++)
#pragma unroll
                    for (int r = 0; r < 4; r++) {
                        float bb = (mkv[kvf][r] != 0.f) ? 0.f : -1e12f;
                        p[kvf][qi][r] = __builtin_fmaf(p[kvf][qi][r], mq01[qi], bb);
                    }
        }

        // ---- lane-local maxima; guard vs m_run + THR ----
        float t[2];
#pragma unroll
        for (int qi = 0; qi < 2; qi++) {
            float a0 = fmaxf(fmaxf(p[0][qi][0], p[0][qi][1]), fmaxf(p[0][qi][2], p[0][qi][3]));
            float a1 = fmaxf(fmaxf(p[1][qi][0], p[1][qi][1]), fmaxf(p[1][qi][2], p[1][qi][3]));
            float a2 = fmaxf(fmaxf(p[2][qi][0], p[2][qi][1]), fmaxf(p[2][qi][2], p[2][qi][3]));
            float a3 = fmaxf(fmaxf(p[3][qi][0], p[3][qi][1]), fmaxf(p[3][qi][2], p[3][qi][3]));
            t[qi] = fmaxf(fmaxf(a0, a1), fmaxf(a2, a3));
        }
        if (!__all((t[0] <= m_run[0] + THR2) && (t[1] <= m_run[1] + THR2))) {
            // cold rescale: cross-lane max, update m_run, scale accumulators
#pragma unroll
            for (int qi = 0; qi < 2; qi++) {
                float tt = fmaxf(t[qi], __shfl_xor(t[qi], 16));
                tt = fmaxf(tt, __shfl_xor(tt, 32));
                float mn = fmaxf(m_run[qi], tt);
                float sc = __builtin_amdgcn_exp2f(m_run[qi] - mn);
                m_run[qi] = mn;
                acc_l[qi] *= sc;
#pragma unroll
                for (int df = 0; df < 4; df++) oaccT[df][qi] *= sc;
            }
        }
        // ---- exp2; m_run==0 fast path has no subtract ----
        if (__all((m_run[0] == 0.f) & (m_run[1] == 0.f))) {
#pragma unroll
            for (int qi = 0; qi < 2; qi++)
#pragma unroll
                for (int kvf = 0; kvf < 4; kvf++)
#pragma unroll
                    for (int r = 0; r < 4; r++)
                        p[kvf][qi][r] = __builtin_amdgcn_exp2f(p[kvf][qi][r]);
        } else {
#pragma unroll
            for (int qi = 0; qi < 2; qi++)
#pragma unroll
                for (int kvf = 0; kvf < 4; kvf++)
#pragma unroll
                    for (int r = 0; r < 4; r++)
                        p[kvf][qi][r] = __builtin_amdgcn_exp2f(p[kvf][qi][r] - m_run[qi]);
        }

        // ---- pb = lane-local P quads packed to bf16 ----
        bf16x8 pb[2][2];
#pragma unroll
        for (int qi = 0; qi < 2; qi++)
#pragma unroll
            for (int kf = 0; kf < 2; kf++) {
                u32x4 tq;
                tq.x = cvtpk(p[2 * kf][qi][0], p[2 * kf][qi][1]);
                tq.y = cvtpk(p[2 * kf][qi][2], p[2 * kf][qi][3]);
                tq.z = cvtpk(p[2 * kf + 1][qi][0], p[2 * kf + 1][qi][1]);
                tq.w = cvtpk(p[2 * kf + 1][qi][2], p[2 * kf + 1][qi][3]);
                pb[qi][kf] = __builtin_bit_cast(bf16x8, tq);
            }

        // V fragments after softmax (kept out of the VALU-phase live set)
        bf16x8 vfr[4][2];
#pragma unroll
        for (int df = 0; df < 4; df++)
#pragma unroll
            for (int kf = 0; kf < 2; kf++) {
                int row = df * 16 + l15;
                int slot = (kf * 4 + l4) ^ (row & 7);
                vfr[df][kf] = *(const bf16x8*)(Vs[cur] + row * 64 + slot * 8);
            }

        // ---- O^T += V^T P^T ; l += ones^T P^T ----
        __builtin_amdgcn_s_setprio(1);
#pragma unroll
        for (int df = 0; df < 4; df++)
#pragma unroll
            for (int qi = 0; qi < 2; qi++)
#pragma unroll
                for (int kf = 0; kf < 2; kf++)
                    oaccT[df][qi] = __builtin_amdgcn_mfma_f32_16x16x32_bf16(vfr[df][kf], pb[qi][kf], oaccT[df][qi], 0, 0, 0);
#pragma unroll
        for (int qi = 0; qi < 2; qi++)
#pragma unroll
            for (int kf = 0; kf < 2; kf++)
                acc_l[qi] = __builtin_amdgcn_mfma_f32_16x16x32_bf16(ones, pb[qi][kf], acc_l[qi], 0, 0, 0);
        __builtin_amdgcn_s_setprio(0);

        __syncthreads();   // drains prefetch vmcnt + protects both dbuf halves
    }

    // ---- epilogue: ctx[token][h*64+d] = O^T / l ----
#pragma unroll
    for (int qi = 0; qi < 2; qi++) {
        float rl = 1.0f / acc_l[qi][0];
        int tok = qw + qi * 16 + l15;
#pragma unroll
        for (int df = 0; df < 4; df++) {
            uint2 o;
            o.x = cvtpk(oaccT[df][qi][0] * rl, oaccT[df][qi][1] * rl);
            o.y = cvtpk(oaccT[df][qi][2] * rl, oaccT[df][qi][3] * rl);
            *(uint2*)(ctx + (size_t)(b * 2048 + tok) * 1024 + h * 64 + df * 16 + l4 * 4) = o;
        }
    }
#undef STAGE_KV
}

extern "C" void kernel_launch(void* const* d_in, const int* in_sizes, int n_in,
                              void* d_out, int out_size, void* d_ws, size_t ws_size,
                              hipStream_t stream) {
    const float* hs    = (const float*)d_in[0];
    const float* masks = (const float*)d_in[1];
    const float* Wq = (const float*)d_in[2];
    const float* bq = (const float*)d_in[3];
    const float* Wk = (const float*)d_in[4];
    const float* bk = (const float*)d_in[5];
    const float* Wv = (const float*)d_in[6];
    const float* bv = (const float*)d_in[7];
    const float* Wo = (const float*)d_in[8];
    const float* bo = (const float*)d_in[9];

    const int NT = 4 * 2048;   // 8192 tokens
    const int H = 1024;

    u16* hs_b = (u16*)d_ws;                       // [8192,1024]
    u16* w_b  = hs_b + (size_t)NT * H;            // [Wq|Wk|Wv|Wo] 4x[1024,1024]
    u16* wo_b = w_b + (size_t)3 * H * H;
    u16* Qb   = w_b + (size_t)4 * H * H;          // [8192,1024] (pre-scaled)
    u16* Kb   = Qb + (size_t)NT * H;              // [8192,1024]
    u16* Vtb  = Kb + (size_t)NT * H;              // [64][64][2048] s'-permuted
    u16* Cb   = hs_b;                             // attn output reuses hidden buffer

    // one fused conversion dispatch: hs + 4 weights into contiguous ws region
    cvt_all<<<12288, 256, 0, stream>>>(hs, Wq, Wk, Wv, Wo, hs_b);

    gemm_qkv<<<1536, 256, 0, stream>>>(hs_b, w_b, bq, bk, bv, Qb, Kb, Vtb);

    attn_fused<<<1024, 256, 0, stream>>>(Qb, Kb, Vtb, masks, Cb);

    gemm_o<<<512, 256, 0, stream>>>(Cb, wo_b, bo, (float*)d_out);
}